// Round 10
// baseline (164.501 us; speedup 1.0000x reference)
//
#include <hip/hip_runtime.h>
#include <hip/hip_bf16.h>

// Problem constants
#define B 32
#define T 4096
#define E 1024
#define H 1024

// ws layout (in floats). qkv: slot0 = v, slot1 = k, slot2 = q
#define ECH        16
#define OFF_QKV    0                               // 3*B*H        =   98304
#define OFF_PART1  (3 * B * H)                     // ECH*B*H      =  524288 (q partials)
#define OFF_SCORES (OFF_PART1 + ECH * B * H)       // B*T          =  131072
#define NTC        32                              // t-chunks (128 rows each)
#define OFF_PART2  (OFF_SCORES + B * T)            // B*NTC*H      = 1048576
#define OFF_CSUM   (OFF_PART2 + B * NTC * H)       // B*NTC        =    1024
#define OFF_STATS  (OFF_CSUM + B * NTC)            // B*2          =      64

// ---------------------------------------------------------------------------
// Kernel 1: q projection partial sums (q-only version of the proven anchor).
// grid (ECH, 16), block 256. Each wave: 64 h-columns, 8 batches, 64 e's.
__global__ void proj_q_partial(const float* __restrict__ x,
                               const float* __restrict__ Wq,
                               float* __restrict__ part) {
    const int ec = blockIdx.x;
    const int hc = blockIdx.y;

    const int wave = threadIdx.x >> 6;
    const int lane = threadIdx.x & 63;
    const int h  = hc * 64 + lane;
    const int b0 = wave * 8;
    const int e0 = ec * 64;

    float acc[8] = {0.f, 0.f, 0.f, 0.f, 0.f, 0.f, 0.f, 0.f};

    for (int eg = 0; eg < 16; ++eg) {
        const int e = e0 + eg * 4;
        const float w0 = Wq[(size_t)(e + 0) * H + h];
        const float w1 = Wq[(size_t)(e + 1) * H + h];
        const float w2 = Wq[(size_t)(e + 2) * H + h];
        const float w3 = Wq[(size_t)(e + 3) * H + h];
#pragma unroll
        for (int j = 0; j < 8; ++j) {
            const float4 xv = *reinterpret_cast<const float4*>(&x[(b0 + j) * E + e]);
            acc[j] += xv.x * w0 + xv.y * w1 + xv.z * w2 + xv.w * w3;
        }
    }
#pragma unroll
    for (int j = 0; j < 8; ++j) {
        part[((size_t)ec * B + (b0 + j)) * H + h] = acc[j];
    }
}

// ---------------------------------------------------------------------------
// Kernel 2: reduce q partials -> qkv slot2. grid 128, block 256.
__global__ void proj_q_reduce(const float* __restrict__ part,
                              float* __restrict__ q) {
    const int idx = blockIdx.x * 256 + threadIdx.x;   // b*H + h
    float s = 0.f;
#pragma unroll
    for (int ec = 0; ec < ECH; ++ec)
        s += part[(size_t)ec * (B * H) + idx];
    q[idx] = s;
}

// ---------------------------------------------------------------------------
// Kernel 3: scores + embedded k,v projection.
// grid (520, B), block 256.
//   blockIdx.x < 512 : scores (UNCHANGED round-3 anchor path; 4 waves,
//                      2 rows/wave, q in regs).
//   blockIdx.x >= 512: k,v projection. 8 blocks x 256 threads = 2048 threads
//                      per batch = one (p,h) column each; runs concurrently
//                      with (hidden under) the 88 us K-stream.
__global__ void scores_kernel(const float* __restrict__ kc,
                              const float* __restrict__ q,
                              const float* __restrict__ x,
                              const float* __restrict__ Wv,
                              const float* __restrict__ Wk,
                              float* __restrict__ qkv,
                              float* __restrict__ scores) {
    const int b = blockIdx.y;

    if (blockIdx.x >= 512) {
        // ---- embedded k,v projection ----
        const int g = (blockIdx.x - 512) * 256 + threadIdx.x;  // 0..2047
        const int p = g >> 10;             // 0 -> v, 1 -> k
        const int h = g & 1023;
        const float* __restrict__ W = p ? Wk : Wv;
        const float* __restrict__ xr = x + (size_t)b * E;
        float acc0 = 0.f, acc1 = 0.f;
        for (int e = 0; e < E; e += 8) {
            const float4 xa = *reinterpret_cast<const float4*>(&xr[e]);
            const float4 xb = *reinterpret_cast<const float4*>(&xr[e + 4]);
            acc0 += xa.x * W[(size_t)(e + 0) * H + h] + xa.y * W[(size_t)(e + 1) * H + h]
                  + xa.z * W[(size_t)(e + 2) * H + h] + xa.w * W[(size_t)(e + 3) * H + h];
            acc1 += xb.x * W[(size_t)(e + 4) * H + h] + xb.y * W[(size_t)(e + 5) * H + h]
                  + xb.z * W[(size_t)(e + 6) * H + h] + xb.w * W[(size_t)(e + 7) * H + h];
        }
        qkv[(size_t)p * (B * H) + (size_t)b * H + h] = acc0 + acc1;
        return;
    }

    // ---- scores path (unchanged) ----
    const int wave = threadIdx.x >> 6;
    const int lane = threadIdx.x & 63;

    const float4* __restrict__ q4 = reinterpret_cast<const float4*>(q + (size_t)b * H);
    float4 qv[4];
#pragma unroll
    for (int g = 0; g < 4; ++g) qv[g] = q4[g * 64 + lane];

#pragma unroll
    for (int r = 0; r < 2; ++r) {
        const int t = blockIdx.x * 8 + wave * 2 + r;
        const float4* __restrict__ row =
            reinterpret_cast<const float4*>(kc + ((size_t)b * T + t) * H);
        float acc = 0.f;
#pragma unroll
        for (int g = 0; g < 4; ++g) {
            const float4 kv = row[g * 64 + lane];
            acc += kv.x * qv[g].x + kv.y * qv[g].y + kv.z * qv[g].z + kv.w * qv[g].w;
        }
#pragma unroll
        for (int m = 32; m; m >>= 1) acc += __shfl_xor(acc, m, 64);
        if (lane == 0) scores[(size_t)b * T + t] = acc;
    }
}

// ---------------------------------------------------------------------------
// Kernel 4: fused softmax + PV with EXACT zero-chunk skipping (UNCHANGED).
// grid (NTC, B), block 256.
__global__ __launch_bounds__(256) void pv_fused(const float* __restrict__ vc,
                                                const float* __restrict__ scores,
                                                const float* __restrict__ qkv,
                                                float* __restrict__ part2,
                                                float* __restrict__ csum,
                                                float* __restrict__ stats) {
    __shared__ float red[256];
    __shared__ float ew[T / NTC];   // 128 unnormalized chunk weights
    __shared__ float wsum[2];
    const int tc = blockIdx.x, b = blockIdx.y, tid = threadIdx.x;
    const int t0 = tc * (T / NTC);

    // appended-token score s_last = dot(q[b], k[b])
    const float4 qv = reinterpret_cast<const float4*>(qkv + 2 * (B * H) + (size_t)b * H)[tid];
    const float4 kv = reinterpret_cast<const float4*>(qkv + 1 * (B * H) + (size_t)b * H)[tid];
    red[tid] = qv.x * kv.x + qv.y * kv.y + qv.z * kv.z + qv.w * kv.w;
    __syncthreads();
    for (int s = 128; s; s >>= 1) {
        if (tid < s) red[tid] += red[tid + s];
        __syncthreads();
    }
    const float s_last = red[0];
    __syncthreads();

    // global max over 4096 scores + s_last (scores are L2-hot, 16 KB/block)
    const float* __restrict__ srow = scores + (size_t)b * T;
    float sc[16];
    float mx = s_last;
#pragma unroll
    for (int i = 0; i < 16; ++i) {
        sc[i] = srow[i * 256 + tid];
        mx = fmaxf(mx, sc[i]);
    }
    red[tid] = mx;
    __syncthreads();
    for (int s = 128; s; s >>= 1) {
        if (tid < s) red[tid] = fmaxf(red[tid], red[tid + s]);
        __syncthreads();
    }
    mx = red[0];
    __syncthreads();

    // denominator
    float sum = 0.f;
#pragma unroll
    for (int i = 0; i < 16; ++i) sum += expf(sc[i] - mx);
    red[tid] = sum;
    __syncthreads();
    for (int s = 128; s; s >>= 1) {
        if (tid < s) red[tid] += red[tid + s];
        __syncthreads();
    }
    const float e_last = expf(s_last - mx);
    const float denom = red[0] + e_last;
    if (tc == 0 && tid == 0) {
        stats[b * 2 + 0] = e_last;
        stats[b * 2 + 1] = denom;
    }
    __syncthreads();

    // own chunk's unnormalized weights + exact-zero sum test
    if (tid < (T / NTC)) ew[tid] = expf(srow[t0 + tid] - mx);
    __syncthreads();
    if (tid < (T / NTC)) {
        float w = ew[tid];
#pragma unroll
        for (int m = 32; m; m >>= 1) w += __shfl_xor(w, m, 64);
        if ((tid & 63) == 0) wsum[tid >> 6] = w;
    }
    __syncthreads();
    const float total = wsum[0] + wsum[1];
    if (tid == 0) csum[(size_t)b * NTC + tc] = total;
    if (total <= 0.0f) return;    // weights >= 0: sum==0 iff all exactly 0

    // V accumulate (unnormalized); finalize divides by denom
    const float4* __restrict__ vrow =
        reinterpret_cast<const float4*>(vc + ((size_t)b * T + t0) * H);
    float4 acc = {0.f, 0.f, 0.f, 0.f};
#pragma unroll 4
    for (int t = 0; t < (T / NTC); ++t) {
        const float a = ew[t];
        const float4 vv = vrow[(size_t)t * 256 + tid];
        acc.x += a * vv.x; acc.y += a * vv.y;
        acc.z += a * vv.z; acc.w += a * vv.w;
    }
    reinterpret_cast<float4*>(part2 + ((size_t)b * NTC + tc) * H)[tid] = acc;
}

// ---------------------------------------------------------------------------
// Kernel 5: finalize (UNCHANGED). grid 128, block 256; b uniform per block.
__global__ void finalize_kernel(const float* __restrict__ part2,
                                const float* __restrict__ qkv,
                                const float* __restrict__ x,
                                const float* __restrict__ csum,
                                const float* __restrict__ stats,
                                float* __restrict__ out) {
    __shared__ float cs[NTC];
    const int idx = blockIdx.x * 256 + threadIdx.x;  // 0..32767
    const int b = idx >> 10;
    const int h = idx & 1023;
    if (threadIdx.x < NTC) cs[threadIdx.x] = csum[(size_t)b * NTC + threadIdx.x];
    __syncthreads();

    float s = 0.f;
    for (int tc = 0; tc < NTC; ++tc)
        if (cs[tc] > 0.0f)
            s += part2[((size_t)b * NTC + tc) * H + h];
    const float e_last = stats[b * 2 + 0];
    const float denom  = stats[b * 2 + 1];
    const float v = qkv[(size_t)b * H + h];   // slot0: value projection
    out[idx] = (s + e_last * v) / denom * (1.f / 32.f) + x[idx];
}

// ---------------------------------------------------------------------------
extern "C" void kernel_launch(void* const* d_in, const int* in_sizes, int n_in,
                              void* d_out, int out_size, void* d_ws, size_t ws_size,
                              hipStream_t stream) {
    const float* x  = (const float*)d_in[0];
    const float* kc = (const float*)d_in[1];
    const float* vc = (const float*)d_in[2];
    const float* Wv = (const float*)d_in[3];
    const float* Wk = (const float*)d_in[4];
    const float* Wq = (const float*)d_in[5];
    float* out = (float*)d_out;
    float* ws  = (float*)d_ws;

    float* qkv    = ws + OFF_QKV;
    float* part1  = ws + OFF_PART1;
    float* scores = ws + OFF_SCORES;
    float* part2  = ws + OFF_PART2;
    float* csum   = ws + OFF_CSUM;
    float* stats  = ws + OFF_STATS;

    hipLaunchKernelGGL(proj_q_partial, dim3(ECH, 16), dim3(256), 0, stream,
                       x, Wq, part1);
    hipLaunchKernelGGL(proj_q_reduce, dim3(128), dim3(256), 0, stream,
                       part1, qkv + 2 * (B * H));
    hipLaunchKernelGGL(scores_kernel, dim3(520, B), dim3(256), 0, stream,
                       kc, qkv + 2 * (B * H), x, Wv, Wk, qkv, scores);
    hipLaunchKernelGGL(pv_fused, dim3(NTC, B), dim3(256), 0, stream,
                       vc, scores, qkv, part2, csum, stats);
    hipLaunchKernelGGL(finalize_kernel, dim3(128), dim3(256), 0, stream,
                       part2, qkv, x, csum, stats, out);
}

// Round 11
// 149.448 us; speedup vs baseline: 1.1007x; 1.1007x over previous
//
#include <hip/hip_runtime.h>
#include <hip/hip_bf16.h>

// Problem constants
#define B 32
#define T 4096
#define E 1024
#define H 1024

// ws layout (in floats). qkv: slot0 = v, slot1 = k, slot2 = q
#define OFF_QKV    0                               // 3*B*H        =   98304
#define OFF_SCORES (3 * B * H)                     // B*T          =  131072
#define NTC        32                              // t-chunks (128 rows each)
#define OFF_PART2  (OFF_SCORES + B * T)            // B*NTC*H      = 1048576
#define OFF_CSUM   (OFF_PART2 + B * NTC * H)       // B*NTC        =    1024
#define OFF_STATS  (OFF_CSUM + B * NTC)            // B*2          =      64

// ---------------------------------------------------------------------------
// Kernel 1: all three projections, single pass (no partial round-trip).
// grid (16 hc, 32 b, 3 p), block 1024 (16 waves).
// Wave w: partial dot over e in [w*64, w*64+64) for 64 h-columns
// (x[b][e] is wave-uniform -> scalar broadcast; W[e][h] coalesced).
// LDS reduce across the 16 waves in fixed order (deterministic).
__global__ __launch_bounds__(1024) void proj_all(const float* __restrict__ x,
                                                 const float* __restrict__ Wv,
                                                 const float* __restrict__ Wk,
                                                 const float* __restrict__ Wq,
                                                 float* __restrict__ qkv) {
    __shared__ float s[16][64];
    const int hc = blockIdx.x;
    const int b  = blockIdx.y;
    const int p  = blockIdx.z;
    const float* __restrict__ W = (p == 0) ? Wv : ((p == 1) ? Wk : Wq);

    const int wave = threadIdx.x >> 6;
    const int lane = threadIdx.x & 63;
    const int h = hc * 64 + lane;

    const float* __restrict__ xr = x + (size_t)b * E + wave * 64;
    const float* __restrict__ Wc = W + (size_t)(wave * 64) * H + h;

    float acc = 0.f;
#pragma unroll 8
    for (int e = 0; e < 64; ++e)
        acc += xr[e] * Wc[(size_t)e * H];

    s[wave][lane] = acc;
    __syncthreads();

    if (threadIdx.x < 64) {
        float t = 0.f;
#pragma unroll
        for (int w = 0; w < 16; ++w) t += s[w][threadIdx.x];
        qkv[(size_t)p * (B * H) + (size_t)b * H + hc * 64 + threadIdx.x] = t;
    }
}

// ---------------------------------------------------------------------------
// Kernel 2: scores (UNCHANGED round-3 anchor).
// grid (T/8, B), block 256 (4 waves); each wave handles 2 rows; q in regs.
__global__ void scores_kernel(const float* __restrict__ kc,
                              const float* __restrict__ q,
                              float* __restrict__ scores) {
    const int b = blockIdx.y;
    const int wave = threadIdx.x >> 6;
    const int lane = threadIdx.x & 63;

    const float4* __restrict__ q4 = reinterpret_cast<const float4*>(q + (size_t)b * H);
    float4 qv[4];
#pragma unroll
    for (int g = 0; g < 4; ++g) qv[g] = q4[g * 64 + lane];

#pragma unroll
    for (int r = 0; r < 2; ++r) {
        const int t = blockIdx.x * 8 + wave * 2 + r;
        const float4* __restrict__ row =
            reinterpret_cast<const float4*>(kc + ((size_t)b * T + t) * H);
        float acc = 0.f;
#pragma unroll
        for (int g = 0; g < 4; ++g) {
            const float4 kv = row[g * 64 + lane];
            acc += kv.x * qv[g].x + kv.y * qv[g].y + kv.z * qv[g].z + kv.w * qv[g].w;
        }
#pragma unroll
        for (int m = 32; m; m >>= 1) acc += __shfl_xor(acc, m, 64);
        if (lane == 0) scores[(size_t)b * T + t] = acc;
    }
}

// ---------------------------------------------------------------------------
// Kernel 3: fused softmax + PV with EXACT zero-chunk skipping (UNCHANGED).
// grid (NTC, B), block 256.
__global__ __launch_bounds__(256) void pv_fused(const float* __restrict__ vc,
                                                const float* __restrict__ scores,
                                                const float* __restrict__ qkv,
                                                float* __restrict__ part2,
                                                float* __restrict__ csum,
                                                float* __restrict__ stats) {
    __shared__ float red[256];
    __shared__ float ew[T / NTC];   // 128 unnormalized chunk weights
    __shared__ float wsum[2];
    const int tc = blockIdx.x, b = blockIdx.y, tid = threadIdx.x;
    const int t0 = tc * (T / NTC);

    // appended-token score s_last = dot(q[b], k[b])
    const float4 qv = reinterpret_cast<const float4*>(qkv + 2 * (B * H) + (size_t)b * H)[tid];
    const float4 kv = reinterpret_cast<const float4*>(qkv + 1 * (B * H) + (size_t)b * H)[tid];
    red[tid] = qv.x * kv.x + qv.y * kv.y + qv.z * kv.z + qv.w * kv.w;
    __syncthreads();
    for (int s = 128; s; s >>= 1) {
        if (tid < s) red[tid] += red[tid + s];
        __syncthreads();
    }
    const float s_last = red[0];
    __syncthreads();

    // global max over 4096 scores + s_last (scores are L2-hot, 16 KB/block)
    const float* __restrict__ srow = scores + (size_t)b * T;
    float sc[16];
    float mx = s_last;
#pragma unroll
    for (int i = 0; i < 16; ++i) {
        sc[i] = srow[i * 256 + tid];
        mx = fmaxf(mx, sc[i]);
    }
    red[tid] = mx;
    __syncthreads();
    for (int s = 128; s; s >>= 1) {
        if (tid < s) red[tid] = fmaxf(red[tid], red[tid + s]);
        __syncthreads();
    }
    mx = red[0];
    __syncthreads();

    // denominator
    float sum = 0.f;
#pragma unroll
    for (int i = 0; i < 16; ++i) sum += expf(sc[i] - mx);
    red[tid] = sum;
    __syncthreads();
    for (int s = 128; s; s >>= 1) {
        if (tid < s) red[tid] += red[tid + s];
        __syncthreads();
    }
    const float e_last = expf(s_last - mx);
    const float denom = red[0] + e_last;
    if (tc == 0 && tid == 0) {
        stats[b * 2 + 0] = e_last;
        stats[b * 2 + 1] = denom;
    }
    __syncthreads();

    // own chunk's unnormalized weights + exact-zero sum test
    if (tid < (T / NTC)) ew[tid] = expf(srow[t0 + tid] - mx);
    __syncthreads();
    if (tid < (T / NTC)) {
        float w = ew[tid];
#pragma unroll
        for (int m = 32; m; m >>= 1) w += __shfl_xor(w, m, 64);
        if ((tid & 63) == 0) wsum[tid >> 6] = w;
    }
    __syncthreads();
    const float total = wsum[0] + wsum[1];
    if (tid == 0) csum[(size_t)b * NTC + tc] = total;
    if (total <= 0.0f) return;    // weights >= 0: sum==0 iff all exactly 0

    // V accumulate (unnormalized); finalize divides by denom
    const float4* __restrict__ vrow =
        reinterpret_cast<const float4*>(vc + ((size_t)b * T + t0) * H);
    float4 acc = {0.f, 0.f, 0.f, 0.f};
#pragma unroll 4
    for (int t = 0; t < (T / NTC); ++t) {
        const float a = ew[t];
        const float4 vv = vrow[(size_t)t * 256 + tid];
        acc.x += a * vv.x; acc.y += a * vv.y;
        acc.z += a * vv.z; acc.w += a * vv.w;
    }
    reinterpret_cast<float4*>(part2 + ((size_t)b * NTC + tc) * H)[tid] = acc;
}

// ---------------------------------------------------------------------------
// Kernel 4: finalize (UNCHANGED). grid 128, block 256; b uniform per block.
__global__ void finalize_kernel(const float* __restrict__ part2,
                                const float* __restrict__ qkv,
                                const float* __restrict__ x,
                                const float* __restrict__ csum,
                                const float* __restrict__ stats,
                                float* __restrict__ out) {
    __shared__ float cs[NTC];
    const int idx = blockIdx.x * 256 + threadIdx.x;  // 0..32767
    const int b = idx >> 10;
    const int h = idx & 1023;
    if (threadIdx.x < NTC) cs[threadIdx.x] = csum[(size_t)b * NTC + threadIdx.x];
    __syncthreads();

    float s = 0.f;
    for (int tc = 0; tc < NTC; ++tc)
        if (cs[tc] > 0.0f)
            s += part2[((size_t)b * NTC + tc) * H + h];
    const float e_last = stats[b * 2 + 0];
    const float denom  = stats[b * 2 + 1];
    const float v = qkv[(size_t)b * H + h];   // slot0: value projection
    out[idx] = (s + e_last * v) / denom * (1.f / 32.f) + x[idx];
}

// ---------------------------------------------------------------------------
extern "C" void kernel_launch(void* const* d_in, const int* in_sizes, int n_in,
                              void* d_out, int out_size, void* d_ws, size_t ws_size,
                              hipStream_t stream) {
    const float* x  = (const float*)d_in[0];
    const float* kc = (const float*)d_in[1];
    const float* vc = (const float*)d_in[2];
    const float* Wv = (const float*)d_in[3];
    const float* Wk = (const float*)d_in[4];
    const float* Wq = (const float*)d_in[5];
    float* out = (float*)d_out;
    float* ws  = (float*)d_ws;

    float* qkv    = ws + OFF_QKV;
    float* scores = ws + OFF_SCORES;
    float* part2  = ws + OFF_PART2;
    float* csum   = ws + OFF_CSUM;
    float* stats  = ws + OFF_STATS;

    hipLaunchKernelGGL(proj_all, dim3(16, 32, 3), dim3(1024), 0, stream,
                       x, Wv, Wk, Wq, qkv);
    hipLaunchKernelGGL(scores_kernel, dim3(T / 8, B), dim3(256), 0, stream,
                       kc, qkv + 2 * (B * H), scores);
    hipLaunchKernelGGL(pv_fused, dim3(NTC, B), dim3(256), 0, stream,
                       vc, scores, qkv, part2, csum, stats);
    hipLaunchKernelGGL(finalize_kernel, dim3(128), dim3(256), 0, stream,
                       part2, qkv, x, csum, stats, out);
}

// Round 13
// 126.591 us; speedup vs baseline: 1.2995x; 1.1806x over previous
//
#include <hip/hip_runtime.h>
#include <hip/hip_bf16.h>

// Problem constants
#define B 32
#define T 4096
#define E 1024
#define H 1024

// ws layout (in floats). qkv: slot0 = v, slot1 = k, slot2 = q
#define OFF_QKV    0                               // 3*B*H        =   98304
#define OFF_SCORES (3 * B * H)                     // B*T          =  131072
#define NTC        32                              // t-chunks (128 rows each)
#define OFF_PART2  (OFF_SCORES + B * T)            // B*NTC*H      = 1048576
#define OFF_CSUM   (OFF_PART2 + B * NTC * H)       // B*NTC        =    1024
#define OFF_STATS  (OFF_CSUM + B * NTC)            // B*2          =      64

// native clang vector type for nontemporal builtins (HIP float4 is rejected)
typedef float fx4 __attribute__((ext_vector_type(4)));

// ---------------------------------------------------------------------------
// Kernel 1: all three projections, single pass (UNCHANGED round-11).
// grid (16 hc, 32 b, 3 p), block 1024 (16 waves).
__global__ __launch_bounds__(1024) void proj_all(const float* __restrict__ x,
                                                 const float* __restrict__ Wv,
                                                 const float* __restrict__ Wk,
                                                 const float* __restrict__ Wq,
                                                 float* __restrict__ qkv) {
    __shared__ float s[16][64];
    const int hc = blockIdx.x;
    const int b  = blockIdx.y;
    const int p  = blockIdx.z;
    const float* __restrict__ W = (p == 0) ? Wv : ((p == 1) ? Wk : Wq);

    const int wave = threadIdx.x >> 6;
    const int lane = threadIdx.x & 63;

    const float* __restrict__ xr = x + (size_t)b * E + wave * 64;
    const float* __restrict__ Wc = W + (size_t)(wave * 64) * H + hc * 64 + lane;

    float acc = 0.f;
#pragma unroll 8
    for (int e = 0; e < 64; ++e)
        acc += xr[e] * Wc[(size_t)e * H];

    s[wave][lane] = acc;
    __syncthreads();

    if (threadIdx.x < 64) {
        float t = 0.f;
#pragma unroll
        for (int w = 0; w < 16; ++w) t += s[w][threadIdx.x];
        qkv[(size_t)p * (B * H) + (size_t)b * H + hc * 64 + threadIdx.x] = t;
    }
}

// ---------------------------------------------------------------------------
// Kernel 2: scores. ONLY change vs round 11: kc reads are NON-TEMPORAL
// (use-once 512 MB stream should not allocate in cache). Native fx4 vector
// type so the builtin accepts the pointer.
// grid (T/8, B), block 256 (4 waves); each wave handles 2 rows; q in regs.
__global__ void scores_kernel(const float* __restrict__ kc,
                              const float* __restrict__ q,
                              float* __restrict__ scores) {
    const int b = blockIdx.y;
    const int wave = threadIdx.x >> 6;
    const int lane = threadIdx.x & 63;

    const float4* __restrict__ q4 = reinterpret_cast<const float4*>(q + (size_t)b * H);
    float4 qv[4];
#pragma unroll
    for (int g = 0; g < 4; ++g) qv[g] = q4[g * 64 + lane];

#pragma unroll
    for (int r = 0; r < 2; ++r) {
        const int t = blockIdx.x * 8 + wave * 2 + r;
        const fx4* __restrict__ row =
            reinterpret_cast<const fx4*>(kc + ((size_t)b * T + t) * H);
        float acc = 0.f;
#pragma unroll
        for (int g = 0; g < 4; ++g) {
            const fx4 kv = __builtin_nontemporal_load(&row[g * 64 + lane]);
            acc += kv.x * qv[g].x + kv.y * qv[g].y + kv.z * qv[g].z + kv.w * qv[g].w;
        }
#pragma unroll
        for (int m = 32; m; m >>= 1) acc += __shfl_xor(acc, m, 64);
        if (lane == 0) scores[(size_t)b * T + t] = acc;
    }
}

// ---------------------------------------------------------------------------
// Kernel 3: fused softmax + PV with EXACT zero-chunk skipping (UNCHANGED).
// grid (NTC, B), block 256.
__global__ __launch_bounds__(256) void pv_fused(const float* __restrict__ vc,
                                                const float* __restrict__ scores,
                                                const float* __restrict__ qkv,
                                                float* __restrict__ part2,
                                                float* __restrict__ csum,
                                                float* __restrict__ stats) {
    __shared__ float red[256];
    __shared__ float ew[T / NTC];   // 128 unnormalized chunk weights
    __shared__ float wsum[2];
    const int tc = blockIdx.x, b = blockIdx.y, tid = threadIdx.x;
    const int t0 = tc * (T / NTC);

    // appended-token score s_last = dot(q[b], k[b])
    const float4 qv = reinterpret_cast<const float4*>(qkv + 2 * (B * H) + (size_t)b * H)[tid];
    const float4 kv = reinterpret_cast<const float4*>(qkv + 1 * (B * H) + (size_t)b * H)[tid];
    red[tid] = qv.x * kv.x + qv.y * kv.y + qv.z * kv.z + qv.w * kv.w;
    __syncthreads();
    for (int s = 128; s; s >>= 1) {
        if (tid < s) red[tid] += red[tid + s];
        __syncthreads();
    }
    const float s_last = red[0];
    __syncthreads();

    // global max over 4096 scores + s_last (scores are L2-hot, 16 KB/block)
    const float* __restrict__ srow = scores + (size_t)b * T;
    float sc[16];
    float mx = s_last;
#pragma unroll
    for (int i = 0; i < 16; ++i) {
        sc[i] = srow[i * 256 + tid];
        mx = fmaxf(mx, sc[i]);
    }
    red[tid] = mx;
    __syncthreads();
    for (int s = 128; s; s >>= 1) {
        if (tid < s) red[tid] = fmaxf(red[tid], red[tid + s]);
        __syncthreads();
    }
    mx = red[0];
    __syncthreads();

    // denominator
    float sum = 0.f;
#pragma unroll
    for (int i = 0; i < 16; ++i) sum += expf(sc[i] - mx);
    red[tid] = sum;
    __syncthreads();
    for (int s = 128; s; s >>= 1) {
        if (tid < s) red[tid] += red[tid + s];
        __syncthreads();
    }
    const float e_last = expf(s_last - mx);
    const float denom = red[0] + e_last;
    if (tc == 0 && tid == 0) {
        stats[b * 2 + 0] = e_last;
        stats[b * 2 + 1] = denom;
    }
    __syncthreads();

    // own chunk's unnormalized weights + exact-zero sum test
    if (tid < (T / NTC)) ew[tid] = expf(srow[t0 + tid] - mx);
    __syncthreads();
    if (tid < (T / NTC)) {
        float w = ew[tid];
#pragma unroll
        for (int m = 32; m; m >>= 1) w += __shfl_xor(w, m, 64);
        if ((tid & 63) == 0) wsum[tid >> 6] = w;
    }
    __syncthreads();
    const float total = wsum[0] + wsum[1];
    if (tid == 0) csum[(size_t)b * NTC + tc] = total;
    if (total <= 0.0f) return;    // weights >= 0: sum==0 iff all exactly 0

    // V accumulate (unnormalized); finalize divides by denom
    const float4* __restrict__ vrow =
        reinterpret_cast<const float4*>(vc + ((size_t)b * T + t0) * H);
    float4 acc = {0.f, 0.f, 0.f, 0.f};
#pragma unroll 4
    for (int t = 0; t < (T / NTC); ++t) {
        const float a = ew[t];
        const float4 vv = vrow[(size_t)t * 256 + tid];
        acc.x += a * vv.x; acc.y += a * vv.y;
        acc.z += a * vv.z; acc.w += a * vv.w;
    }
    reinterpret_cast<float4*>(part2 + ((size_t)b * NTC + tc) * H)[tid] = acc;
}

// ---------------------------------------------------------------------------
// Kernel 4: finalize (UNCHANGED). grid 128, block 256; b uniform per block.
__global__ void finalize_kernel(const float* __restrict__ part2,
                                const float* __restrict__ qkv,
                                const float* __restrict__ x,
                                const float* __restrict__ csum,
                                const float* __restrict__ stats,
                                float* __restrict__ out) {
    __shared__ float cs[NTC];
    const int idx = blockIdx.x * 256 + threadIdx.x;  // 0..32767
    const int b = idx >> 10;
    const int h = idx & 1023;
    if (threadIdx.x < NTC) cs[threadIdx.x] = csum[(size_t)b * NTC + threadIdx.x];
    __syncthreads();

    float s = 0.f;
    for (int tc = 0; tc < NTC; ++tc)
        if (cs[tc] > 0.0f)
            s += part2[((size_t)b * NTC + tc) * H + h];
    const float e_last = stats[b * 2 + 0];
    const float denom  = stats[b * 2 + 1];
    const float v = qkv[(size_t)b * H + h];   // slot0: value projection
    out[idx] = (s + e_last * v) / denom * (1.f / 32.f) + x[idx];
}

// ---------------------------------------------------------------------------
extern "C" void kernel_launch(void* const* d_in, const int* in_sizes, int n_in,
                              void* d_out, int out_size, void* d_ws, size_t ws_size,
                              hipStream_t stream) {
    const float* x  = (const float*)d_in[0];
    const float* kc = (const float*)d_in[1];
    const float* vc = (const float*)d_in[2];
    const float* Wv = (const float*)d_in[3];
    const float* Wk = (const float*)d_in[4];
    const float* Wq = (const float*)d_in[5];
    float* out = (float*)d_out;
    float* ws  = (float*)d_ws;

    float* qkv    = ws + OFF_QKV;
    float* scores = ws + OFF_SCORES;
    float* part2  = ws + OFF_PART2;
    float* csum   = ws + OFF_CSUM;
    float* stats  = ws + OFF_STATS;

    hipLaunchKernelGGL(proj_all, dim3(16, 32, 3), dim3(1024), 0, stream,
                       x, Wv, Wk, Wq, qkv);
    hipLaunchKernelGGL(scores_kernel, dim3(T / 8, B), dim3(256), 0, stream,
                       kc, qkv + 2 * (B * H), scores);
    hipLaunchKernelGGL(pv_fused, dim3(NTC, B), dim3(256), 0, stream,
                       vc, scores, qkv, part2, csum, stats);
    hipLaunchKernelGGL(finalize_kernel, dim3(128), dim3(256), 0, stream,
                       part2, qkv, x, csum, stats, out);
}